// Round 3
// baseline (808.605 us; speedup 1.0000x reference)
//
#include <hip/hip_runtime.h>
#include <hip/hip_bf16.h>

#define HID 768
#define DW  200
#define NW  5

// ===========================================================================
// Algebraic restructuring (saves 2.1x FLOPs vs naive):
//   TH  = tanh(WE @ W1 + b1)                  [40960, 768]   12.6 GF
//   G   = attn_W @ W2^T                       [768, 768]      0.9 GF
//   P2  = LO @ G                              [8192, 768]     9.7 GF
//   scores[t,n] = TH[t,n,:] . P2[t,:]   (+ const-in-n term -> cancels in softmax)
//   attn = softmax(mask ? -1e9 : scores)
//   ATH[t,:] = sum_n attn[t,n] * TH[t,n,:]
//   out = LN(LO + ATH @ W2 + b2)   (sum_n attn = 1 absorbs b2)   9.7 GF
// ===========================================================================

// ---------------------------------------------------------------------------
// Kernel A: TH = tanh(WE @ W1 + b1). 16 rows/block; WE tile transposed in LDS
// (broadcast ds_read_b128 in k-loop); W1 streamed from L2. 48 FMA : 3 loads.
// ---------------------------------------------------------------------------
template<int TM>
__global__ __launch_bounds__(256)
void mlp1_kernel(const float* __restrict__ WE,
                 const float* __restrict__ W1,
                 const float* __restrict__ b1,
                 float* __restrict__ TH)
{
    __shared__ __align__(16) float weT[DW][TM];  // 12.8 KB
    const int tid = threadIdx.x;
    const long row0 = (long)blockIdx.x * TM;

    {
        const float4* src = reinterpret_cast<const float4*>(WE + row0 * DW);
        for (int i = tid; i < TM * (DW / 4); i += 256) {
            int t = i / (DW / 4), k4 = i % (DW / 4);
            float4 v = src[(size_t)t * (DW / 4) + k4];
            weT[k4 * 4 + 0][t] = v.x; weT[k4 * 4 + 1][t] = v.y;
            weT[k4 * 4 + 2][t] = v.z; weT[k4 * 4 + 3][t] = v.w;
        }
    }
    __syncthreads();

    float acc[TM][3];
    #pragma unroll
    for (int t = 0; t < TM; ++t) { acc[t][0] = 0.f; acc[t][1] = 0.f; acc[t][2] = 0.f; }

    #pragma unroll 2
    for (int k = 0; k < DW; ++k) {
        float a[TM];
        #pragma unroll
        for (int q = 0; q < TM / 4; ++q) {
            float4 v = *reinterpret_cast<const float4*>(&weT[k][q * 4]);
            a[q * 4 + 0] = v.x; a[q * 4 + 1] = v.y; a[q * 4 + 2] = v.z; a[q * 4 + 3] = v.w;
        }
        float w0 = W1[(size_t)k * HID + tid];
        float w1 = W1[(size_t)k * HID + 256 + tid];
        float w2 = W1[(size_t)k * HID + 512 + tid];
        #pragma unroll
        for (int t = 0; t < TM; ++t) {
            acc[t][0] = fmaf(a[t], w0, acc[t][0]);
            acc[t][1] = fmaf(a[t], w1, acc[t][1]);
            acc[t][2] = fmaf(a[t], w2, acc[t][2]);
        }
    }

    #pragma unroll
    for (int c = 0; c < 3; ++c) {
        int j = c * 256 + tid;
        float bb = b1[j];
        #pragma unroll
        for (int t = 0; t < TM; ++t)
            TH[(row0 + t) * HID + j] = tanhf(acc[t][c] + bb);
    }
}

// ---------------------------------------------------------------------------
// Kernel B: G[d,h] = sum_e attn_W[d,e] * W2[h,e]  (NT GEMM, 768^3, tiny).
// 64x64 tile/block, 16x16 threads x (4x4), K-tile 32, both operands staged
// transposed in LDS (stride 68 floats: 16B-aligned rows, conflict-reduced).
// ---------------------------------------------------------------------------
__global__ __launch_bounds__(256)
void gw_kernel(const float* __restrict__ A,
               const float* __restrict__ W2,
               float* __restrict__ G)
{
    __shared__ __align__(16) float AsT[32][68];
    __shared__ __align__(16) float WsT[32][68];
    const int tid = threadIdx.x;
    const int bd = blockIdx.x / (HID / 64), bh = blockIdx.x % (HID / 64);
    const int d0 = bd * 64, h0 = bh * 64;
    const int tx = tid % 16, ty = tid / 16;

    float acc[4][4];
    #pragma unroll
    for (int i = 0; i < 4; ++i)
        #pragma unroll
        for (int j = 0; j < 4; ++j) acc[i][j] = 0.f;

    for (int e0 = 0; e0 < HID; e0 += 32) {
        __syncthreads();
        #pragma unroll
        for (int q = 0; q < 2; ++q) {
            int idx = q * 256 + tid;       // 0..511 over 64 rows x 8 float4
            int r = idx / 8, c4 = idx % 8;
            float4 va = *reinterpret_cast<const float4*>(&A [(size_t)(d0 + r) * HID + e0 + c4 * 4]);
            AsT[c4 * 4 + 0][r] = va.x; AsT[c4 * 4 + 1][r] = va.y;
            AsT[c4 * 4 + 2][r] = va.z; AsT[c4 * 4 + 3][r] = va.w;
            float4 vw = *reinterpret_cast<const float4*>(&W2[(size_t)(h0 + r) * HID + e0 + c4 * 4]);
            WsT[c4 * 4 + 0][r] = vw.x; WsT[c4 * 4 + 1][r] = vw.y;
            WsT[c4 * 4 + 2][r] = vw.z; WsT[c4 * 4 + 3][r] = vw.w;
        }
        __syncthreads();
        #pragma unroll 4
        for (int e = 0; e < 32; ++e) {
            float4 a4 = *reinterpret_cast<const float4*>(&AsT[e][ty * 4]);
            float4 b4 = *reinterpret_cast<const float4*>(&WsT[e][tx * 4]);
            float av[4] = {a4.x, a4.y, a4.z, a4.w};
            float bv[4] = {b4.x, b4.y, b4.z, b4.w};
            #pragma unroll
            for (int i = 0; i < 4; ++i)
                #pragma unroll
                for (int j = 0; j < 4; ++j)
                    acc[i][j] = fmaf(av[i], bv[j], acc[i][j]);
        }
    }
    #pragma unroll
    for (int i = 0; i < 4; ++i) {
        float4 o = {acc[i][0], acc[i][1], acc[i][2], acc[i][3]};
        *reinterpret_cast<float4*>(&G[(size_t)(d0 + ty * 4 + i) * HID + h0 + tx * 4]) = o;
    }
}

// ---------------------------------------------------------------------------
// Kernel C: P2 = LO @ G. 8 tokens/block, LO tile transposed in LDS,
// G streamed from L2. 24 FMA : 3 loads.
// ---------------------------------------------------------------------------
template<int TT>
__global__ __launch_bounds__(256)
void proj_kernel(const float* __restrict__ LO,
                 const float* __restrict__ G,
                 float* __restrict__ P2)
{
    __shared__ __align__(16) float loT[HID][TT];  // 24.6 KB
    const int tid = threadIdx.x;
    const long tok0 = (long)blockIdx.x * TT;

    {
        const float4* src = reinterpret_cast<const float4*>(LO + tok0 * HID);
        for (int i = tid; i < TT * (HID / 4); i += 256) {
            int t = i / (HID / 4), k4 = i % (HID / 4);
            float4 v = src[(size_t)t * (HID / 4) + k4];
            loT[k4 * 4 + 0][t] = v.x; loT[k4 * 4 + 1][t] = v.y;
            loT[k4 * 4 + 2][t] = v.z; loT[k4 * 4 + 3][t] = v.w;
        }
    }
    __syncthreads();

    float acc[TT][3];
    #pragma unroll
    for (int t = 0; t < TT; ++t) { acc[t][0] = 0.f; acc[t][1] = 0.f; acc[t][2] = 0.f; }

    #pragma unroll 2
    for (int k = 0; k < HID; ++k) {
        float a[TT];
        #pragma unroll
        for (int q = 0; q < TT / 4; ++q) {
            float4 v = *reinterpret_cast<const float4*>(&loT[k][q * 4]);
            a[q * 4 + 0] = v.x; a[q * 4 + 1] = v.y; a[q * 4 + 2] = v.z; a[q * 4 + 3] = v.w;
        }
        float w0 = G[(size_t)k * HID + tid];
        float w1 = G[(size_t)k * HID + 256 + tid];
        float w2 = G[(size_t)k * HID + 512 + tid];
        #pragma unroll
        for (int t = 0; t < TT; ++t) {
            acc[t][0] = fmaf(a[t], w0, acc[t][0]);
            acc[t][1] = fmaf(a[t], w1, acc[t][1]);
            acc[t][2] = fmaf(a[t], w2, acc[t][2]);
        }
    }

    #pragma unroll
    for (int c = 0; c < 3; ++c)
        #pragma unroll
        for (int t = 0; t < TT; ++t)
            P2[(tok0 + t) * HID + c * 256 + tid] = acc[t][c];
}

// ---------------------------------------------------------------------------
// Kernel D: scores -> softmax -> ATH -> ATH@W2 + b2 + LO -> LayerNorm.
// 8 tokens/block (4 waves). LDS: p2s [8][768] + athT [768][8] (reused as the
// pre-LN output buffer) = 49.4 KB -> 3 blocks/CU.
// ---------------------------------------------------------------------------
template<int TT>
__global__ __launch_bounds__(256)
void attn_ln2_kernel(const float* __restrict__ LO,
                     const float* __restrict__ TH,
                     const float* __restrict__ P2,
                     const int* __restrict__ mask,
                     const float* __restrict__ W2,
                     const float* __restrict__ b2,
                     const float* __restrict__ gamma,
                     const float* __restrict__ beta,
                     float* __restrict__ out)
{
    __shared__ __align__(16) float p2s[TT][HID];   // 24.6 KB
    __shared__ __align__(16) float athT[HID][TT];  // 24.6 KB (later: outbuf [TT][HID])
    __shared__ float sc_s[TT][NW];
    __shared__ float at_s[TT][NW];
    const int tid = threadIdx.x;
    const long tok0 = (long)blockIdx.x * TT;
    const int wave = tid >> 6, lane = tid & 63;

    // stage P2 tile (flat float4 copy)
    {
        const float4* src = reinterpret_cast<const float4*>(P2 + tok0 * HID);
        float4* dst = reinterpret_cast<float4*>(&p2s[0][0]);
        for (int i = tid; i < TT * (HID / 4); i += 256) dst[i] = src[i];
    }
    __syncthreads();

    // ---- scores: 40 (token, word) dots across 4 waves ----
    for (int pr = wave; pr < TT * NW; pr += 4) {
        int t = pr / NW, n = pr % NW;
        const float* th = TH + ((tok0 + t) * NW + n) * (size_t)HID;
        float s = 0.f;
        #pragma unroll
        for (int it = 0; it < HID / 256; ++it) {
            int k0 = lane * 4 + it * 256;
            float4 p4 = *reinterpret_cast<const float4*>(&p2s[t][k0]);
            float4 w4 = *reinterpret_cast<const float4*>(&th[k0]);
            s = fmaf(p4.x, w4.x, s); s = fmaf(p4.y, w4.y, s);
            s = fmaf(p4.z, w4.z, s); s = fmaf(p4.w, w4.w, s);
        }
        #pragma unroll
        for (int off = 32; off; off >>= 1) s += __shfl_xor(s, off);
        if (lane == 0) sc_s[t][n] = s;
    }
    __syncthreads();

    // ---- masked softmax over N=5 ----
    if (tid < TT) {
        float v[NW]; float m = -3.0e38f;
        #pragma unroll
        for (int n = 0; n < NW; ++n) {
            float sv = (mask[(tok0 + tid) * NW + n] != 0) ? -1.0e9f : sc_s[tid][n];
            v[n] = sv; m = fmaxf(m, sv);
        }
        float sum = 0.f;
        #pragma unroll
        for (int n = 0; n < NW; ++n) { float e = expf(v[n] - m); v[n] = e; sum += e; }
        float inv = 1.0f / sum;
        #pragma unroll
        for (int n = 0; n < NW; ++n) at_s[tid][n] = v[n] * inv;
    }
    __syncthreads();

    // ---- ATH (transposed in LDS): athT[h][t] = sum_n attn[t,n]*TH[t,n,h] ----
    for (int i = tid; i < TT * HID; i += 256) {
        int t = i / HID, h = i % HID;
        const float* th = TH + ((tok0 + t) * NW) * (size_t)HID + h;
        float v = 0.f;
        #pragma unroll
        for (int n = 0; n < NW; ++n) v = fmaf(at_s[t][n], th[n * HID], v);
        athT[h][t] = v;
    }
    __syncthreads();

    // ---- GEMM2: acc = ATH @ W2 ----
    float acc[TT][3];
    #pragma unroll
    for (int t = 0; t < TT; ++t) { acc[t][0] = 0.f; acc[t][1] = 0.f; acc[t][2] = 0.f; }

    #pragma unroll 2
    for (int k = 0; k < HID; ++k) {
        float a[TT];
        #pragma unroll
        for (int q = 0; q < TT / 4; ++q) {
            float4 v = *reinterpret_cast<const float4*>(&athT[k][q * 4]);
            a[q * 4 + 0] = v.x; a[q * 4 + 1] = v.y; a[q * 4 + 2] = v.z; a[q * 4 + 3] = v.w;
        }
        float w0 = W2[(size_t)k * HID + tid];
        float w1 = W2[(size_t)k * HID + 256 + tid];
        float w2 = W2[(size_t)k * HID + 512 + tid];
        #pragma unroll
        for (int t = 0; t < TT; ++t) {
            acc[t][0] = fmaf(a[t], w0, acc[t][0]);
            acc[t][1] = fmaf(a[t], w1, acc[t][1]);
            acc[t][2] = fmaf(a[t], w2, acc[t][2]);
        }
    }
    __syncthreads();  // done reading athT; reuse it as pre-LN output buffer

    float* outb = &athT[0][0];  // [TT][HID] view
    #pragma unroll
    for (int c = 0; c < 3; ++c) {
        int j = c * 256 + tid;
        float bb = b2[j];
        #pragma unroll
        for (int t = 0; t < TT; ++t)
            outb[t * HID + j] = acc[t][c] + bb + LO[(tok0 + t) * HID + j];
    }
    __syncthreads();

    // ---- LayerNorm: one wave per 2 tokens ----
    for (int tt = 0; tt < TT / 4; ++tt) {
        int t = wave * (TT / 4) + tt;
        float vals[HID / 64];
        #pragma unroll
        for (int i = 0; i < HID / 64; ++i) vals[i] = outb[t * HID + lane + i * 64];
        float s = 0.f;
        #pragma unroll
        for (int i = 0; i < HID / 64; ++i) s += vals[i];
        #pragma unroll
        for (int off = 32; off; off >>= 1) s += __shfl_xor(s, off);
        float mu = s * (1.0f / HID);
        float q = 0.f;
        #pragma unroll
        for (int i = 0; i < HID / 64; ++i) { float d = vals[i] - mu; q = fmaf(d, d, q); }
        #pragma unroll
        for (int off = 32; off; off >>= 1) q += __shfl_xor(q, off);
        float rs = rsqrtf(q * (1.0f / HID) + 1e-12f);
        #pragma unroll
        for (int i = 0; i < HID / 64; ++i) {
            int h = lane + i * 64;
            out[(tok0 + t) * HID + h] = (vals[i] - mu) * rs * gamma[h] + beta[h];
        }
    }
}

// ---------------------------------------------------------------------------
extern "C" void kernel_launch(void* const* d_in, const int* in_sizes, int n_in,
                              void* d_out, int out_size, void* d_ws, size_t ws_size,
                              hipStream_t stream)
{
    const float* LO    = (const float*)d_in[0];  // [16,512,768]
    const float* WE    = (const float*)d_in[1];  // [16,512,5,200]
    const int*   mask  = (const int*)  d_in[2];  // [16,512,5]
    const float* W1    = (const float*)d_in[3];  // [200,768]
    const float* b1    = (const float*)d_in[4];  // [768]
    const float* W2    = (const float*)d_in[5];  // [768,768]
    const float* b2    = (const float*)d_in[6];  // [768]
    const float* attnW = (const float*)d_in[7];  // [768,768]
    const float* gamma = (const float*)d_in[8];  // [768]
    const float* beta  = (const float*)d_in[9];  // [768]
    float* out = (float*)d_out;                  // [16,512,768]

    const int R = 16 * 512 * NW;  // 40960 word rows
    const int T = 16 * 512;       // 8192 tokens

    // workspace layout (floats): TH [R,768] | P2 [T,768] | G [768,768]
    float* TH = (float*)d_ws;
    float* P2 = TH + (size_t)R * HID;
    float* G  = P2 + (size_t)T * HID;

    constexpr int TM = 16;  // word-rows per block (kernel A)
    constexpr int TT = 8;   // tokens per block (kernels C, D)

    gw_kernel<<<(HID / 64) * (HID / 64), 256, 0, stream>>>(attnW, W2, G);
    mlp1_kernel<TM><<<R / TM, 256, 0, stream>>>(WE, W1, b1, TH);
    proj_kernel<TT><<<T / TT, 256, 0, stream>>>(LO, G, P2);
    attn_ln2_kernel<TT><<<T / TT, 256, 0, stream>>>(LO, TH, P2, mask, W2, b2, gamma, beta, out);
}

// Round 9
// 687.725 us; speedup vs baseline: 1.1758x; 1.1758x over previous
//
#include <hip/hip_runtime.h>
#include <hip/hip_bf16.h>

#define HID 768
#define DW  200
#define NW  5

// ===========================================================================
// Structure (all fp32; 2.1x-FLOP-reduced algebra from R2, now TH-in-registers):
//   G   = attn_W @ W2^T          [768,768]   (gw_kernel, tiny)
//   P2  = LO @ G                 [8192,768]  (proj_kernel)
//   fused_kernel (per block: 8 tokens = 2 groups x 4 tokens):
//     per group g:
//       th[20][3] (regs) = tanh(WE_tile @ W1 + b1)     <- never hits HBM
//       scores[t,n] = th . p2  (reg FMA + shuffle reduce)
//       attn = masked softmax (N=5)
//       athT[:, g*4+tt] = sum_n attn*th                -> LDS [768][8]
//     GEMM2: acc = athT @ W2   (24 FMA : 3 L2 loads)
//     out = LN(acc + b2 + LO) * gamma + beta
// ===========================================================================

// ---------------------------------------------------------------------------
// Kernel B: G[d,h] = sum_e attn_W[d,e] * W2[h,e]  (NT GEMM, 768^3, tiny).
// ---------------------------------------------------------------------------
__global__ __launch_bounds__(256)
void gw_kernel(const float* __restrict__ A,
               const float* __restrict__ W2,
               float* __restrict__ G)
{
    __shared__ __align__(16) float AsT[32][68];
    __shared__ __align__(16) float WsT[32][68];
    const int tid = threadIdx.x;
    const int bd = blockIdx.x / (HID / 64), bh = blockIdx.x % (HID / 64);
    const int d0 = bd * 64, h0 = bh * 64;
    const int tx = tid % 16, ty = tid / 16;

    float acc[4][4];
    #pragma unroll
    for (int i = 0; i < 4; ++i)
        #pragma unroll
        for (int j = 0; j < 4; ++j) acc[i][j] = 0.f;

    for (int e0 = 0; e0 < HID; e0 += 32) {
        __syncthreads();
        #pragma unroll
        for (int q = 0; q < 2; ++q) {
            int idx = q * 256 + tid;
            int r = idx / 8, c4 = idx % 8;
            float4 va = *reinterpret_cast<const float4*>(&A [(size_t)(d0 + r) * HID + e0 + c4 * 4]);
            AsT[c4 * 4 + 0][r] = va.x; AsT[c4 * 4 + 1][r] = va.y;
            AsT[c4 * 4 + 2][r] = va.z; AsT[c4 * 4 + 3][r] = va.w;
            float4 vw = *reinterpret_cast<const float4*>(&W2[(size_t)(h0 + r) * HID + e0 + c4 * 4]);
            WsT[c4 * 4 + 0][r] = vw.x; WsT[c4 * 4 + 1][r] = vw.y;
            WsT[c4 * 4 + 2][r] = vw.z; WsT[c4 * 4 + 3][r] = vw.w;
        }
        __syncthreads();
        #pragma unroll 4
        for (int e = 0; e < 32; ++e) {
            float4 a4 = *reinterpret_cast<const float4*>(&AsT[e][ty * 4]);
            float4 b4 = *reinterpret_cast<const float4*>(&WsT[e][tx * 4]);
            float av[4] = {a4.x, a4.y, a4.z, a4.w};
            float bv[4] = {b4.x, b4.y, b4.z, b4.w};
            #pragma unroll
            for (int i = 0; i < 4; ++i)
                #pragma unroll
                for (int j = 0; j < 4; ++j)
                    acc[i][j] = fmaf(av[i], bv[j], acc[i][j]);
        }
    }
    #pragma unroll
    for (int i = 0; i < 4; ++i) {
        float4 o = {acc[i][0], acc[i][1], acc[i][2], acc[i][3]};
        *reinterpret_cast<float4*>(&G[(size_t)(d0 + ty * 4 + i) * HID + h0 + tx * 4]) = o;
    }
}

// ---------------------------------------------------------------------------
// Kernel C: P2 = LO @ G. 8 tokens/block.
// ---------------------------------------------------------------------------
template<int TT>
__global__ __launch_bounds__(256)
void proj_kernel(const float* __restrict__ LO,
                 const float* __restrict__ G,
                 float* __restrict__ P2)
{
    __shared__ __align__(16) float loT[HID][TT];
    const int tid = threadIdx.x;
    const long tok0 = (long)blockIdx.x * TT;

    {
        const float4* src = reinterpret_cast<const float4*>(LO + tok0 * HID);
        for (int i = tid; i < TT * (HID / 4); i += 256) {
            int t = i / (HID / 4), k4 = i % (HID / 4);
            float4 v = src[(size_t)t * (HID / 4) + k4];
            loT[k4 * 4 + 0][t] = v.x; loT[k4 * 4 + 1][t] = v.y;
            loT[k4 * 4 + 2][t] = v.z; loT[k4 * 4 + 3][t] = v.w;
        }
    }
    __syncthreads();

    float acc[TT][3];
    #pragma unroll
    for (int t = 0; t < TT; ++t) { acc[t][0] = 0.f; acc[t][1] = 0.f; acc[t][2] = 0.f; }

    #pragma unroll 2
    for (int k = 0; k < HID; ++k) {
        float a[TT];
        #pragma unroll
        for (int q = 0; q < TT / 4; ++q) {
            float4 v = *reinterpret_cast<const float4*>(&loT[k][q * 4]);
            a[q * 4 + 0] = v.x; a[q * 4 + 1] = v.y; a[q * 4 + 2] = v.z; a[q * 4 + 3] = v.w;
        }
        float w0 = G[(size_t)k * HID + tid];
        float w1 = G[(size_t)k * HID + 256 + tid];
        float w2 = G[(size_t)k * HID + 512 + tid];
        #pragma unroll
        for (int t = 0; t < TT; ++t) {
            acc[t][0] = fmaf(a[t], w0, acc[t][0]);
            acc[t][1] = fmaf(a[t], w1, acc[t][1]);
            acc[t][2] = fmaf(a[t], w2, acc[t][2]);
        }
    }

    #pragma unroll
    for (int c = 0; c < 3; ++c)
        #pragma unroll
        for (int t = 0; t < TT; ++t)
            P2[(tok0 + t) * HID + c * 256 + tid] = acc[t][c];
}

// ---------------------------------------------------------------------------
// Kernel D (fused): MLP1-in-regs + scores + softmax + ATH + GEMM2 + LN.
// 8 tokens/block in 2 groups of 4. LDS = 53.6 KB -> 3 blocks/CU.
// ---------------------------------------------------------------------------
__global__ __launch_bounds__(256)
void fused_kernel(const float* __restrict__ WE,
                  const float* __restrict__ W1,
                  const float* __restrict__ b1,
                  const float* __restrict__ W2,
                  const float* __restrict__ b2,
                  const float* __restrict__ LO,
                  const float* __restrict__ P2,
                  const int* __restrict__ mask,
                  const float* __restrict__ gamma,
                  const float* __restrict__ beta,
                  float* __restrict__ out)
{
    __shared__ __align__(16) float weT[DW * 20];     // 16000 B, [k][r] r=0..19
    __shared__ __align__(16) float p2s[4][HID];      // 12288 B
    __shared__ __align__(16) float athT[HID * 8];    // 24576 B, [k][token 0..7]
    __shared__ float red[4][32];
    __shared__ float sc_s[4][NW];
    __shared__ float at_s[4][NW];
    __shared__ float mus[8], rss[8];

    const int tid = threadIdx.x;
    const int wave = tid >> 6, lane = tid & 63;
    const long tok0 = (long)blockIdx.x * 8;

    #pragma unroll 1
    for (int g = 0; g < 2; ++g) {
        const long tokg = tok0 + g * 4;
        const long rowg = tokg * NW;     // 20 word-rows for this group

        __syncthreads();   // previous group done with weT/p2s before restage

        // ---- stage WE tile transposed ([k][r]) + P2 tile (flat) ----
        for (int i = tid; i < 20 * (DW / 4); i += 256) {
            int r = i / (DW / 4), k4 = i % (DW / 4);
            float4 v = *reinterpret_cast<const float4*>(&WE[(rowg + r) * DW + k4 * 4]);
            weT[(k4 * 4 + 0) * 20 + r] = v.x;
            weT[(k4 * 4 + 1) * 20 + r] = v.y;
            weT[(k4 * 4 + 2) * 20 + r] = v.z;
            weT[(k4 * 4 + 3) * 20 + r] = v.w;
        }
        {
            const float4* src = reinterpret_cast<const float4*>(P2 + tokg * HID);
            float4* dst = reinterpret_cast<float4*>(&p2s[0][0]);
            for (int i = tid; i < 4 * (HID / 4); i += 256) dst[i] = src[i];
        }
        __syncthreads();

        // ---- MLP1: th[r][c] over this thread's 3 columns j = c*256+tid ----
        float th[20][3];
        #pragma unroll
        for (int r = 0; r < 20; ++r) { th[r][0] = 0.f; th[r][1] = 0.f; th[r][2] = 0.f; }

        #pragma unroll 2
        for (int k = 0; k < DW; ++k) {
            float a[20];
            #pragma unroll
            for (int q = 0; q < 5; ++q) {
                float4 v = *reinterpret_cast<const float4*>(&weT[k * 20 + q * 4]);
                a[q * 4 + 0] = v.x; a[q * 4 + 1] = v.y; a[q * 4 + 2] = v.z; a[q * 4 + 3] = v.w;
            }
            float w0 = W1[(size_t)k * HID + tid];
            float w1 = W1[(size_t)k * HID + 256 + tid];
            float w2 = W1[(size_t)k * HID + 512 + tid];
            #pragma unroll
            for (int r = 0; r < 20; ++r) {
                th[r][0] = fmaf(a[r], w0, th[r][0]);
                th[r][1] = fmaf(a[r], w1, th[r][1]);
                th[r][2] = fmaf(a[r], w2, th[r][2]);
            }
        }
        {
            float bb0 = b1[tid], bb1 = b1[256 + tid], bb2 = b1[512 + tid];
            #pragma unroll
            for (int r = 0; r < 20; ++r) {
                th[r][0] = tanhf(th[r][0] + bb0);
                th[r][1] = tanhf(th[r][1] + bb1);
                th[r][2] = tanhf(th[r][2] + bb2);
            }
        }

        // ---- scores: ps[tt][n] = sum_j th*p2 ; shuffle + cross-wave reduce ----
        {
            float p2v[4][3];
            #pragma unroll
            for (int tt = 0; tt < 4; ++tt) {
                p2v[tt][0] = p2s[tt][tid];
                p2v[tt][1] = p2s[tt][256 + tid];
                p2v[tt][2] = p2s[tt][512 + tid];
            }
            #pragma unroll
            for (int tt = 0; tt < 4; ++tt)
                #pragma unroll
                for (int n = 0; n < NW; ++n) {
                    int r = tt * NW + n;
                    float s = th[r][0] * p2v[tt][0];
                    s = fmaf(th[r][1], p2v[tt][1], s);
                    s = fmaf(th[r][2], p2v[tt][2], s);
                    #pragma unroll
                    for (int off = 32; off; off >>= 1) s += __shfl_xor(s, off);
                    if (lane == 0) red[wave][r] = s;
                }
        }
        __syncthreads();
        if (tid < 20) {
            float s = red[0][tid] + red[1][tid] + red[2][tid] + red[3][tid];
            sc_s[tid / NW][tid % NW] = s;
        }
        __syncthreads();

        // ---- masked softmax over N=5 ----
        if (tid < 4) {
            float v[NW]; float m = -3.0e38f;
            #pragma unroll
            for (int n = 0; n < NW; ++n) {
                float sv = (mask[(tokg + tid) * NW + n] != 0) ? -1.0e9f : sc_s[tid][n];
                v[n] = sv; m = fmaxf(m, sv);
            }
            float sum = 0.f;
            #pragma unroll
            for (int n = 0; n < NW; ++n) { float e = expf(v[n] - m); v[n] = e; sum += e; }
            float inv = 1.0f / sum;
            #pragma unroll
            for (int n = 0; n < NW; ++n) at_s[tid][n] = v[n] * inv;
        }
        __syncthreads();

        // ---- ATH (registers) -> athT[k][g*4+tt] ----
        #pragma unroll
        for (int tt = 0; tt < 4; ++tt) {
            float a0 = 0.f, a1 = 0.f, a2 = 0.f;
            #pragma unroll
            for (int n = 0; n < NW; ++n) {
                float w = at_s[tt][n];
                a0 = fmaf(w, th[tt * NW + n][0], a0);
                a1 = fmaf(w, th[tt * NW + n][1], a1);
                a2 = fmaf(w, th[tt * NW + n][2], a2);
            }
            int col = g * 4 + tt;
            athT[(0 * 256 + tid) * 8 + col] = a0;
            athT[(1 * 256 + tid) * 8 + col] = a1;
            athT[(2 * 256 + tid) * 8 + col] = a2;
        }
    }
    __syncthreads();

    // ---- GEMM2: acc[t][c] = sum_k athT[k][t] * W2[k][j] ----
    float acc[8][3];
    #pragma unroll
    for (int t = 0; t < 8; ++t) { acc[t][0] = 0.f; acc[t][1] = 0.f; acc[t][2] = 0.f; }

    #pragma unroll 4
    for (int k = 0; k < HID; ++k) {
        float4 a0 = *reinterpret_cast<const float4*>(&athT[k * 8]);
        float4 a1 = *reinterpret_cast<const float4*>(&athT[k * 8 + 4]);
        float w0 = W2[(size_t)k * HID + tid];
        float w1 = W2[(size_t)k * HID + 256 + tid];
        float w2 = W2[(size_t)k * HID + 512 + tid];
        acc[0][0] = fmaf(a0.x, w0, acc[0][0]); acc[0][1] = fmaf(a0.x, w1, acc[0][1]); acc[0][2] = fmaf(a0.x, w2, acc[0][2]);
        acc[1][0] = fmaf(a0.y, w0, acc[1][0]); acc[1][1] = fmaf(a0.y, w1, acc[1][1]); acc[1][2] = fmaf(a0.y, w2, acc[1][2]);
        acc[2][0] = fmaf(a0.z, w0, acc[2][0]); acc[2][1] = fmaf(a0.z, w1, acc[2][1]); acc[2][2] = fmaf(a0.z, w2, acc[2][2]);
        acc[3][0] = fmaf(a0.w, w0, acc[3][0]); acc[3][1] = fmaf(a0.w, w1, acc[3][1]); acc[3][2] = fmaf(a0.w, w2, acc[3][2]);
        acc[4][0] = fmaf(a1.x, w0, acc[4][0]); acc[4][1] = fmaf(a1.x, w1, acc[4][1]); acc[4][2] = fmaf(a1.x, w2, acc[4][2]);
        acc[5][0] = fmaf(a1.y, w0, acc[5][0]); acc[5][1] = fmaf(a1.y, w1, acc[5][1]); acc[5][2] = fmaf(a1.y, w2, acc[5][2]);
        acc[6][0] = fmaf(a1.z, w0, acc[6][0]); acc[6][1] = fmaf(a1.z, w1, acc[6][1]); acc[6][2] = fmaf(a1.z, w2, acc[6][2]);
        acc[7][0] = fmaf(a1.w, w0, acc[7][0]); acc[7][1] = fmaf(a1.w, w1, acc[7][1]); acc[7][2] = fmaf(a1.w, w2, acc[7][2]);
    }

    // ---- + b2 + LO residual ----
    float v[8][3];
    {
        float bb0 = b2[tid], bb1 = b2[256 + tid], bb2 = b2[512 + tid];
        #pragma unroll
        for (int t = 0; t < 8; ++t) {
            v[t][0] = acc[t][0] + bb0 + LO[(tok0 + t) * HID + tid];
            v[t][1] = acc[t][1] + bb1 + LO[(tok0 + t) * HID + 256 + tid];
            v[t][2] = acc[t][2] + bb2 + LO[(tok0 + t) * HID + 512 + tid];
        }
    }

    // ---- LayerNorm reductions (sum, sumsq per token) ----
    #pragma unroll
    for (int t = 0; t < 8; ++t) {
        float s = v[t][0] + v[t][1] + v[t][2];
        float q = v[t][0] * v[t][0];
        q = fmaf(v[t][1], v[t][1], q);
        q = fmaf(v[t][2], v[t][2], q);
        #pragma unroll
        for (int off = 32; off; off >>= 1) { s += __shfl_xor(s, off); q += __shfl_xor(q, off); }
        if (lane == 0) { red[wave][t] = s; red[wave][8 + t] = q; }
    }
    __syncthreads();
    if (tid < 8) {
        float S = red[0][tid] + red[1][tid] + red[2][tid] + red[3][tid];
        float Q = red[0][8 + tid] + red[1][8 + tid] + red[2][8 + tid] + red[3][8 + tid];
        float mu = S * (1.0f / HID);
        float var = Q * (1.0f / HID) - mu * mu;
        mus[tid] = mu;
        rss[tid] = rsqrtf(var + 1e-12f);
    }
    __syncthreads();

    {
        float g0 = gamma[tid], g1 = gamma[256 + tid], g2 = gamma[512 + tid];
        float e0 = beta[tid],  e1 = beta[256 + tid],  e2 = beta[512 + tid];
        #pragma unroll
        for (int t = 0; t < 8; ++t) {
            float mu = mus[t], rs = rss[t];
            out[(tok0 + t) * HID + tid]       = (v[t][0] - mu) * rs * g0 + e0;
            out[(tok0 + t) * HID + 256 + tid] = (v[t][1] - mu) * rs * g1 + e1;
            out[(tok0 + t) * HID + 512 + tid] = (v[t][2] - mu) * rs * g2 + e2;
        }
    }
}

// ---------------------------------------------------------------------------
extern "C" void kernel_launch(void* const* d_in, const int* in_sizes, int n_in,
                              void* d_out, int out_size, void* d_ws, size_t ws_size,
                              hipStream_t stream)
{
    const float* LO    = (const float*)d_in[0];  // [16,512,768]
    const float* WE    = (const float*)d_in[1];  // [16,512,5,200]
    const int*   mask  = (const int*)  d_in[2];  // [16,512,5]
    const float* W1    = (const float*)d_in[3];  // [200,768]
    const float* b1    = (const float*)d_in[4];  // [768]
    const float* W2    = (const float*)d_in[5];  // [768,768]
    const float* b2    = (const float*)d_in[6];  // [768]
    const float* attnW = (const float*)d_in[7];  // [768,768]
    const float* gamma = (const float*)d_in[8];  // [768]
    const float* beta  = (const float*)d_in[9];  // [768]
    float* out = (float*)d_out;                  // [16,512,768]

    const int T = 16 * 512;  // 8192 tokens

    // workspace (floats): P2 [T,768] | G [768,768]   (~27.6 MB)
    float* P2 = (float*)d_ws;
    float* G  = P2 + (size_t)T * HID;

    gw_kernel<<<(HID / 64) * (HID / 64), 256, 0, stream>>>(attnW, W2, G);
    proj_kernel<8><<<T / 8, 256, 0, stream>>>(LO, G, P2);
    fused_kernel<<<T / 8, 256, 0, stream>>>(WE, W1, b1, W2, b2, LO, P2, mask, gamma, beta, out);
}